// Round 1
// baseline (33.771 us; speedup 1.0000x reference)
//
#include <hip/hip_runtime.h>

#define NPIX 65536            // 256*256
#define SC   (10000.0f / 280.0f)
#define TC   (300.0f / 280.0f)

__global__ __launch_bounds__(256) void rpfq_kernel(
    const float* __restrict__ Offset,   // (B,3,65536)
    const float* __restrict__ Q,        // (B,4)
    const float* __restrict__ T,        // (B,3)
    const float* __restrict__ mean,     // (3,65536)
    float* __restrict__ out)            // (B,3,65536)
{
    const int b     = blockIdx.x >> 6;       // 64 blocks per batch
    const int chunk = blockIdx.x & 63;
    const int pix4  = chunk * 256 + threadIdx.x;   // index into float4-view of a channel

    // ---- per-batch coefficients (b uniform per block -> scalar loads) ----
    const float q0 = Q[b * 4 + 0] * 0.05f;
    const float q1 = Q[b * 4 + 1] * 0.05f;
    const float q2 = Q[b * 4 + 2] * 0.05f;
    const float q3 = Q[b * 4 + 3] * 0.05f;

    const float r00 = q0*q0 + q1*q1 - q2*q2 - q3*q3;
    const float r01 = 2.0f * (q1*q2 + q0*q3);
    const float r02 = 2.0f * (q1*q3 - q0*q2);
    const float r10 = 2.0f * (q1*q2 - q0*q3);
    const float r11 = q0*q0 - q1*q1 + q2*q2 - q3*q3;
    const float r12 = 2.0f * (q0*q1 + q2*q3);
    const float r20 = 2.0f * (q0*q2 + q1*q3);
    const float r21 = 2.0f * (q2*q3 - q0*q1);
    const float r22 = q0*q0 - q1*q1 - q2*q2 + q3*q3;

    // A[d][c] = rot[d][c] * sign(c) * 10000/280, sign(1) = -1
    const float a00 =  r00 * SC, a01 = -r01 * SC, a02 =  r02 * SC;
    const float a10 =  r10 * SC, a11 = -r11 * SC, a12 =  r12 * SC;
    const float a20 =  r20 * SC, a21 = -r21 * SC, a22 =  r22 * SC;

    const float t0 = T[b * 3 + 0] * TC;
    const float t1 = T[b * 3 + 1] * TC;
    const float t2 = T[b * 3 + 2] * TC;

    // ---- per-pixel work: 4 pixels via float4 ----
    const size_t base = (size_t)b * 3 * NPIX;
    const float4 o0 = ((const float4*)(Offset + base          ))[pix4];
    const float4 o1 = ((const float4*)(Offset + base +   NPIX ))[pix4];
    const float4 o2 = ((const float4*)(Offset + base + 2*NPIX ))[pix4];
    const float4 m0 = ((const float4*)(mean          ))[pix4];
    const float4 m1 = ((const float4*)(mean +   NPIX ))[pix4];
    const float4 m2 = ((const float4*)(mean + 2*NPIX ))[pix4];

    float4 y0, y1, y2;
    {
        // lane-wise: p_c = 4*o_c + m_c ; y_d = a_d0*p0 + a_d1*p1 + a_d2*p2 + t_d
        #define DO(comp)                                                      \
        {                                                                     \
            const float p0 = fmaf(4.0f, o0.comp, m0.comp);                    \
            const float p1 = fmaf(4.0f, o1.comp, m1.comp);                    \
            const float p2 = fmaf(4.0f, o2.comp, m2.comp);                    \
            y0.comp = fmaf(a00, p0, fmaf(a01, p1, fmaf(a02, p2, t0)));        \
            y1.comp = fmaf(a10, p0, fmaf(a11, p1, fmaf(a12, p2, t1)));        \
            y2.comp = fmaf(a20, p0, fmaf(a21, p1, fmaf(a22, p2, t2)));        \
        }
        DO(x) DO(y) DO(z) DO(w)
        #undef DO
    }

    ((float4*)(out + base          ))[pix4] = y0;
    ((float4*)(out + base +   NPIX ))[pix4] = y1;
    ((float4*)(out + base + 2*NPIX ))[pix4] = y2;
}

extern "C" void kernel_launch(void* const* d_in, const int* in_sizes, int n_in,
                              void* d_out, int out_size, void* d_ws, size_t ws_size,
                              hipStream_t stream) {
    const float* Offset = (const float*)d_in[0];   // (128,3,256,256)
    const float* Q      = (const float*)d_in[1];   // (128,4)
    const float* T      = (const float*)d_in[2];   // (128,3)
    const float* mean   = (const float*)d_in[3];   // (3,256,256)
    float* out          = (float*)d_out;           // (128,3,256,256)

    const int B = in_sizes[1] / 4;                 // 128
    const int blocks = B * 64;                     // 64 chunks of 1024 px per batch
    rpfq_kernel<<<blocks, 256, 0, stream>>>(Offset, Q, T, mean, out);
}